// Round 10
// baseline (359.037 us; speedup 1.0000x reference)
//
#include <hip/hip_runtime.h>
#include <hip/hip_bf16.h>

#define B_   256
#define S_   2048
#define DIN  128
#define H_   64
#define SD_  5
#define GDT  16            // steps per group (= one staging tile)
#define NTT  (S_ / GDT)    // 128 groups
#define DD   3             // correction delay in groups (48 steps, A^48)
#define TOKB 256           // tokens per phaseA block
#define NIT  4             // tiles per wave in phaseA

typedef __attribute__((ext_vector_type(8))) short short8_t;   // 8 bf16
typedef __attribute__((ext_vector_type(4))) float float4_t;   // MFMA acc

__device__ __forceinline__ float rcpf_(float x){ return __builtin_amdgcn_rcpf(x); }

// exact-erf GELU: gelu(x)=0.5x(1+erf(x/sqrt2)), A&S 7.1.26
__device__ __forceinline__ float geluf(float v){
  const float kInvSqrt2 = 0.70710678118654752440f;
  float z = v * kInvSqrt2;
  float a = fabsf(z);
  float t = rcpf_(fmaf(0.3275911f, a, 1.0f));
  float p = fmaf(fmaf(fmaf(fmaf(1.061405429f, t, -1.453152027f), t, 1.421413741f),
                      t, -0.284496736f), t, 0.254829592f);
  p *= t;
  float e = 1.0f - p * __expf(-z * z);
  float er = copysignf(e, z);
  return 0.5f * v * (1.0f + er);
}

__device__ __forceinline__ float sigmoidf_(float x){
  return rcpf_(1.0f + __expf(-x));
}

// Pade(3,2) tanh with clamp: |err| <= 0.0065 (attenuated x0.01 by corr_scale)
__device__ __forceinline__ float tanh_pade(float x){
  float xc = fminf(fmaxf(x, -4.0f), 4.0f);
  float t = xc * xc;
  float n = xc * (27.0f + t);
  float d = fmaf(9.0f, t, 27.0f);
  return n * rcpf_(d);
}

__device__ __forceinline__ unsigned short f2bf_hw(float f){
  union { __hip_bfloat16 b; unsigned short u; } cv;
  cv.b = __float2bfloat16(f);
  return cv.u;
}
__device__ __forceinline__ float bf2f(unsigned short h){
  return __uint_as_float(((unsigned int)h) << 16);
}

// ---- async global->LDS ----
__device__ __forceinline__ void gl_lds16(const void* g, void* l){
  __builtin_amdgcn_global_load_lds(
      (const __attribute__((address_space(1))) void*)g,
      (__attribute__((address_space(3))) void*)l, 16, 0, 0);
}
__device__ __forceinline__ void gl_lds4(const void* g, void* l){
  __builtin_amdgcn_global_load_lds(
      (const __attribute__((address_space(1))) void*)g,
      (__attribute__((address_space(3))) void*)l, 4, 0, 0);
}

// ---- DPP helpers ----
template<int CTRL>
__device__ __forceinline__ float dpp_radd(float x){
  int sh = __builtin_amdgcn_update_dpp(0, __float_as_int(x), CTRL, 0xf, 0xf, true);
  return x + __int_as_float(sh);
}
__device__ __forceinline__ float red16(float x){
  x = dpp_radd<0xB1>(x);   // quad_perm xor1
  x = dpp_radd<0x4E>(x);   // quad_perm xor2
  x = dpp_radd<0x124>(x);  // row_ror:4
  x = dpp_radd<0x128>(x);  // row_ror:8
  return x;
}

// ---------------------------------------------------------------------------
// Phase A (unchanged, MFMA-based)
// ---------------------------------------------------------------------------
__global__ __launch_bounds__(256, 4) void phaseA(
    const float* __restrict__ x, const float* __restrict__ W_in,
    const float* __restrict__ b_in, const float* __restrict__ ln_g,
    const float* __restrict__ ln_b, const float* __restrict__ W_innov,
    const float* __restrict__ b_innov, const float* __restrict__ W_c1,
    const float* __restrict__ b_c1,
    unsigned short* __restrict__ hp_out, float* __restrict__ bx_out)
{
  __shared__ __align__(16) unsigned short WfA[4][4][512];
  __shared__ __align__(16) unsigned short WfC[2][4][512];
  __shared__ __align__(16) unsigned short WfI[2][512];
  __shared__ __align__(16) unsigned short hbuf[4][16][72];

  const int tid  = threadIdx.x;
  const int lane = tid & 63;
  const int w    = tid >> 6;
  const int c16  = lane & 15;
  const int g4   = lane >> 4;
  const long tok0 = (long)blockIdx.x * TOKB;

  {
    const int l = lane, tg = w;
    #pragma unroll
    for (int pp = 0; pp < 4; ++pp){
      int p  = tg * 4 + pp;
      int kc = p >> 2, nc = p & 3;
      unsigned short tmp[8];
      #pragma unroll
      for (int m = 0; m < 8; ++m)
        tmp[m] = f2bf_hw(W_in[(32 * kc + 8 * (l >> 4) + m) * 64 + 16 * nc + (l & 15)]);
      *(uint4*)&WfA[kc][nc][l * 8] = *(uint4*)tmp;
    }
    #pragma unroll
    for (int pp = 0; pp < 2; ++pp){
      int p  = tg * 2 + pp;
      int kc2 = p >> 2, nc = p & 3;
      unsigned short tmp[8];
      #pragma unroll
      for (int m = 0; m < 8; ++m)
        tmp[m] = f2bf_hw(W_c1[(5 + 32 * kc2 + 8 * (l >> 4) + m) * 64 + 16 * nc + (l & 15)]);
      *(uint4*)&WfC[kc2][nc][l * 8] = *(uint4*)tmp;
    }
    if (tg < 2){
      int kc2 = tg;
      unsigned short tmp[8];
      #pragma unroll
      for (int m = 0; m < 8; ++m)
        tmp[m] = ((l & 15) < 5)
               ? f2bf_hw(W_innov[(32 * kc2 + 8 * (l >> 4) + m) * 5 + (l & 15)])
               : (unsigned short)0;
      *(uint4*)&WfI[kc2][l * 8] = *(uint4*)tmp;
    }
  }

  float binv[4], lg[4], lb[4], bc1v[4];
  #pragma unroll
  for (int nc = 0; nc < 4; ++nc){
    binv[nc] = b_in[16 * nc + c16];
    lg[nc]   = ln_g[16 * nc + c16];
    lb[nc]   = ln_b[16 * nc + c16];
    bc1v[nc] = b_c1[16 * nc + c16];
  }
  float binn = (c16 < 5) ? b_innov[c16] : 0.0f;

  __syncthreads();

  for (int it = 0; it < NIT; ++it){
    const long tbg = tok0 + it * 64 + w * 16;

    const float* xr = x + (size_t)(tbg + c16) * DIN;
    short8_t a1[4];
    #pragma unroll
    for (int kc = 0; kc < 4; ++kc){
      float4 f0 = *(const float4*)(xr + kc * 32 + g4 * 8);
      float4 f1 = *(const float4*)(xr + kc * 32 + g4 * 8 + 4);
      a1[kc][0] = (short)f2bf_hw(f0.x); a1[kc][1] = (short)f2bf_hw(f0.y);
      a1[kc][2] = (short)f2bf_hw(f0.z); a1[kc][3] = (short)f2bf_hw(f0.w);
      a1[kc][4] = (short)f2bf_hw(f1.x); a1[kc][5] = (short)f2bf_hw(f1.y);
      a1[kc][6] = (short)f2bf_hw(f1.z); a1[kc][7] = (short)f2bf_hw(f1.w);
    }

    float4_t acc1[4] = {{0,0,0,0},{0,0,0,0},{0,0,0,0},{0,0,0,0}};
    #pragma unroll
    for (int kc = 0; kc < 4; ++kc){
      #pragma unroll
      for (int nc = 0; nc < 4; ++nc){
        short8_t bf = *(const short8_t*)&WfA[kc][nc][lane * 8];
        acc1[nc] = __builtin_amdgcn_mfma_f32_16x16x32_bf16(a1[kc], bf, acc1[nc], 0, 0, 0);
      }
    }

    float v[4][4];
    #pragma unroll
    for (int nc = 0; nc < 4; ++nc)
      #pragma unroll
      for (int r = 0; r < 4; ++r)
        v[nc][r] = acc1[nc][r] + binv[nc];

    float mu[4], rstd[4];
    #pragma unroll
    for (int r = 0; r < 4; ++r){
      float vs = (v[0][r] + v[1][r]) + (v[2][r] + v[3][r]);
      float qs = v[0][r] * v[0][r];
      qs = fmaf(v[1][r], v[1][r], qs);
      qs = fmaf(v[2][r], v[2][r], qs);
      qs = fmaf(v[3][r], v[3][r], qs);
      vs = red16(vs);
      qs = red16(qs);
      float m  = vs * (1.0f / 64.0f);
      float va = fmaxf(qs * (1.0f / 64.0f) - m * m, 0.0f);
      mu[r]   = m;
      rstd[r] = rsqrtf(va + 1e-5f);
    }

    #pragma unroll
    for (int nc = 0; nc < 4; ++nc)
      #pragma unroll
      for (int r = 0; r < 4; ++r){
        float hn = fmaf((v[nc][r] - mu[r]) * rstd[r], lg[nc], lb[nc]);
        hbuf[w][4 * g4 + r][16 * nc + c16] = f2bf_hw(geluf(hn));
      }

    short8_t a2[2];
    a2[0] = *(const short8_t*)&hbuf[w][c16][8 * g4];
    a2[1] = *(const short8_t*)&hbuf[w][c16][32 + 8 * g4];

    float4_t acc2[4] = {{0,0,0,0},{0,0,0,0},{0,0,0,0},{0,0,0,0}};
    #pragma unroll
    for (int kc2 = 0; kc2 < 2; ++kc2){
      #pragma unroll
      for (int nc = 0; nc < 4; ++nc){
        short8_t bf = *(const short8_t*)&WfC[kc2][nc][lane * 8];
        acc2[nc] = __builtin_amdgcn_mfma_f32_16x16x32_bf16(a2[kc2], bf, acc2[nc], 0, 0, 0);
      }
    }
    float4_t acc3 = {0, 0, 0, 0};
    {
      short8_t bi0 = *(const short8_t*)&WfI[0][lane * 8];
      short8_t bi1 = *(const short8_t*)&WfI[1][lane * 8];
      acc3 = __builtin_amdgcn_mfma_f32_16x16x32_bf16(a2[0], bi0, acc3, 0, 0, 0);
      acc3 = __builtin_amdgcn_mfma_f32_16x16x32_bf16(a2[1], bi1, acc3, 0, 0, 0);
    }

    if (c16 < 5){
      #pragma unroll
      for (int r = 0; r < 4; ++r)
        bx_out[(size_t)(tbg + 4 * g4 + r) * 8 + c16] = acc3[r] + binn;
    }

    #pragma unroll
    for (int nc = 0; nc < 4; ++nc)
      #pragma unroll
      for (int r = 0; r < 4; ++r)
        hbuf[w][4 * g4 + r][16 * nc + c16] = f2bf_hw(acc2[nc][r] + bc1v[nc]);

    {
      const int tl = lane >> 2, j = lane & 3;
      uint4 v0 = *(const uint4*)&hbuf[w][tl][j * 16];
      uint4 v1 = *(const uint4*)&hbuf[w][tl][j * 16 + 8];
      unsigned short* hg = hp_out + (size_t)(tbg + tl) * 64 + j * 16;
      *(uint4*)hg       = v0;
      *(uint4*)(hg + 8) = v1;
    }
  }
}

// ---------------------------------------------------------------------------
// Phase B: GD=16 groups, corrections injected THREE groups late (48 steps,
// A^48 twist). Per-iteration order RECUR(t) . CORR(t-1) puts a full iteration
// of independent work between every LDS publish and its consumer:
//   crR: CORR(t-3) -> RECUR(t)  (gap = iter t-1)
//   uT : RECUR(t-1) -> CORR(t-1) (gap = RECUR(t))
// 3-slot crR ring (slot g%3); uT double-buffered (g&1); exact 48-step Horner
// tail over the last 3 groups' corrections.
// ---------------------------------------------------------------------------
__global__ __launch_bounds__(64, 1) void phaseB(
    const unsigned short* __restrict__ hp, const float* __restrict__ bx,
    const float* __restrict__ W_c1, const float* __restrict__ W_c2,
    const float* __restrict__ b_c2, const float* __restrict__ corr_scale,
    const float* __restrict__ rawL, const float* __restrict__ rawT,
    const float* __restrict__ rawG, const float* __restrict__ rawR,
    const float* __restrict__ omega, float* __restrict__ out)
{
  __shared__ __align__(16) unsigned short hpT[2][GDT][64];  // 4 KB
  __shared__ __align__(16) float bxT[2][GDT][8];            // 1 KB
  __shared__ __align__(16) unsigned short uT[2][GDT][64];   // 4 KB (swizzled cols)
  __shared__ __align__(16) float crR[3][GDT][8];            // 1.5 KB ring

  const int lane = threadIdx.x;
  const int b = blockIdx.x;
  const int c16 = lane & 15;
  const int g4  = lane >> 4;

  // zero-init the correction ring (3*16*8 = 384 floats)
  #pragma unroll
  for (int i = 0; i < 6; ++i)
    ((float*)crR)[lane + 64 * i] = 0.f;

  float aL = sigmoidf_(rawL[0]) * 0.15f + 0.85f;
  float aT = sigmoidf_(rawT[0]) * 0.25f + 0.70f;
  float gg = sigmoidf_(rawG[0]) * 0.20f + 0.80f;
  float om = omega[0];
  float co = cosf(om), sn = sinf(om);
  float r00 = gg * co, r01 = -gg * sn, r10 = gg * sn, r11 = gg * co;
  float aR = sigmoidf_(rawR[0]) * 0.4f;
  float cs = corr_scale[0];

  // A^48 for the 3-group (48-step) delayed injection
  auto p16 = [](float v){ float t = v * v; t = t * t; t = t * t; return t * t; };
  float aL16 = p16(aL), aT16 = p16(aT), aR16 = p16(aR), g16 = p16(gg);
  float aL48 = aL16 * aL16 * aL16;
  float aT48 = aT16 * aT16 * aT16;
  float aR48 = aR16 * aR16 * aR16;
  float g48  = g16 * g16 * g16;
  float ck = cosf(48.0f * om), sk = sinf(48.0f * om);
  float p00 = g48 * ck, p01 = -g48 * sk, p10 = g48 * sk, p11 = g48 * ck;

  float w0 = W_c1[0 * 64 + lane], w1 = W_c1[1 * 64 + lane], w2 = W_c1[2 * 64 + lane];
  float w3 = W_c1[3 * 64 + lane], w4 = W_c1[4 * 64 + lane];
  float bc0 = b_c2[0], bc1 = b_c2[1], bc2v = b_c2[2], bc3 = b_c2[3], bc4 = b_c2[4];
  float bcs0 = (g4 == 1) ? bc4 : bc0;   // acc reg0 = row i=4*g4

  // static A-frags: W_c2^T (rows i=c16<5 else 0), K split j 0..31 / 32..63
  short8_t aF0, aF1;
  #pragma unroll
  for (int m = 0; m < 8; ++m){
    int j0 = 8 * g4 + m;
    float v0 = (c16 < 5) ? W_c2[j0 * 5 + c16] : 0.0f;
    float v1 = (c16 < 5) ? W_c2[(j0 + 32) * 5 + c16] : 0.0f;
    aF0[m] = (short)f2bf_hw(v0);
    aF1[m] = (short)f2bf_hw(v1);
  }

  const unsigned short* hpg = hp + (size_t)b * S_ * H_;
  const float* bxg = bx + (size_t)b * S_ * 8;

  float s0 = 0.f, s1 = 0.f, s2 = 0.f, s3 = 0.f, s4 = 0.f;

  auto ISSUE = [&](int t, int nb){
    const unsigned short* g0 = hpg + (size_t)t * (GDT * 64) + lane * 8;
    gl_lds16(g0,       &hpT[nb][0][0]);
    gl_lds16(g0 + 512, &hpT[nb][8][0]);
    const float* g1 = bxg + (size_t)t * (GDT * 8) + lane;
    gl_lds4(g1,      &bxT[nb][0][0]);
    gl_lds4(g1 + 64, &bxT[nb][8][0]);
  };

  // 16-step recursion; reads crR[rs] (published 3 groups ago), stages u into
  // uT[ub]. The s-chain is the only loop-carried dependency.
  auto RECUR = [&](int rs, int ub, int tbuf){
    float4 cp[GDT]; float cp4[GDT];
    #pragma unroll
    for (int k = 0; k < GDT; ++k){
      cp[k]  = *(const float4*)&crR[rs][k][0];
      cp4[k] = crR[rs][k][4];
    }
    float hk[GDT], e4v[GDT]; float4 xb[GDT];
    #pragma unroll
    for (int k = 0; k < GDT; ++k){
      hk[k]  = bf2f(hpT[tbuf][k][lane]);
      xb[k]  = *(const float4*)&bxT[tbuf][k][0];
      e4v[k] = bxT[tbuf][k][4];
    }
    float i0[GDT], i1[GDT], i2[GDT], i3[GDT], i4[GDT];
    #pragma unroll
    for (int k = 0; k < GDT; ++k){
      i0[k] = fmaf(cp[k].x, aL48, xb[k].x);
      i1[k] = fmaf(cp[k].y, aT48, xb[k].y);
      i2[k] = fmaf(cp[k].z, p00, fmaf(cp[k].w, p10, xb[k].z));
      i3[k] = fmaf(cp[k].z, p01, fmaf(cp[k].w, p11, xb[k].w));
      i4[k] = fmaf(cp4[k], aR48, e4v[k]);
    }
    float n0[GDT], n1[GDT], n2[GDT], n3[GDT], n4[GDT];
    #pragma unroll
    for (int k = 0; k < GDT; ++k){
      n0[k] = fmaf(s0, aL, i0[k]);
      n1[k] = fmaf(s1, aT, i1[k]);
      n2[k] = fmaf(s2, r00, fmaf(s3, r10, i2[k]));
      n3[k] = fmaf(s2, r01, fmaf(s3, r11, i3[k]));
      n4[k] = fmaf(s4, aR, i4[k]);
      s0 = n0[k]; s1 = n1[k]; s2 = n2[k]; s3 = n3[k]; s4 = n4[k];
    }
    #pragma unroll
    for (int k = 0; k < GDT; ++k){
      float u = fmaf(n0[k], w0, hk[k]);
      u = fmaf(n1[k], w1, u);
      u = fmaf(n2[k], w2, u);
      u = fmaf(n3[k], w3, u);
      u = fmaf(n4[k], w4, u);
      float uu = u * rcpf_(1.0f + __expf(-1.702f * u));   // sigmoid-GELU
      const int jsw = lane ^ ((k & 7) << 3);
      uT[ub][k][jsw] = (unsigned short)(__float_as_uint(uu) >> 16);
    }
  };

  auto CORR = [&](int ws, int ub){
    const int blk0 = (g4 ^ (c16 & 7)) * 8;
    const int blk1 = ((4 + g4) ^ (c16 & 7)) * 8;
    short8_t b0 = *(const short8_t*)&uT[ub][c16][blk0];
    short8_t b1 = *(const short8_t*)&uT[ub][c16][blk1];
    float4_t acc = {0.f, 0.f, 0.f, 0.f};
    acc = __builtin_amdgcn_mfma_f32_16x16x32_bf16(aF0, b0, acc, 0, 0, 0);
    acc = __builtin_amdgcn_mfma_f32_16x16x32_bf16(aF1, b1, acc, 0, 0, 0);
    float d0 = cs * tanh_pade(acc[0] + bcs0);
    float d1 = cs * tanh_pade(acc[1] + bc1);
    float d2 = cs * tanh_pade(acc[2] + bc2v);
    float d3 = cs * tanh_pade(acc[3] + bc3);
    if (g4 == 0)
      *(float4*)&crR[ws][c16][0] = make_float4(d0, d1, d2, d3);  // i=0..3, k=c16
    if (g4 == 1)
      crR[ws][c16][4] = d0;                                      // i=4
  };

  // ---- prologue ----
  ISSUE(0, 0);
  ISSUE(1, 1);
  asm volatile("s_waitcnt vmcnt(4)" ::: "memory");
  __builtin_amdgcn_sched_barrier(0);
  RECUR(0, 0, 0);          // g=0: reads crR[0] (zeros), stages uT[0]
  int rs = 1, ws = 0;

  for (int t = 1; t < NTT; ++t){
    int tn = (t + 1 < NTT) ? (t + 1) : 0;
    ISSUE(tn, (t + 1) & 1);
    asm volatile("s_waitcnt vmcnt(4)" ::: "memory");
    __builtin_amdgcn_sched_barrier(0);
    RECUR(rs, t & 1, t & 1);     // g=t: reads crR[t%3], stages uT[t&1]
    CORR(ws, (t - 1) & 1);       // g=t-1: writes crR[(t-1)%3]
    rs = (rs + 1 == 3) ? 0 : rs + 1;
    ws = (ws + 1 == 3) ? 0 : ws + 1;
  }
  CORR(ws, (NTT - 1) & 1);       // g=NTT-1

  // ---- tail: s_final = s_hat + Horner(last 48 corrections under A) ----
  {
    const int sl[3] = { (NTT - 3) % 3, (NTT - 2) % 3, (NTT - 1) % 3 };
    float v0 = 0.f, v1 = 0.f, v2 = 0.f, v3 = 0.f, v4 = 0.f;
    #pragma unroll
    for (int gi = 0; gi < 3; ++gi){
      const int sli = sl[gi];
      #pragma unroll
      for (int k = 0; k < GDT; ++k){
        float n0 = fmaf(v0, aL, crR[sli][k][0]);
        float n1 = fmaf(v1, aT, crR[sli][k][1]);
        float n2 = fmaf(v2, r00, fmaf(v3, r10, crR[sli][k][2]));
        float n3 = fmaf(v2, r01, fmaf(v3, r11, crR[sli][k][3]));
        float n4 = fmaf(v4, aR, crR[sli][k][4]);
        v0 = n0; v1 = n1; v2 = n2; v3 = n3; v4 = n4;
      }
    }
    if (lane == 0){
      float* o = out + b * SD_;
      o[0] = s0 + v0; o[1] = s1 + v1; o[2] = s2 + v2;
      o[3] = s3 + v3; o[4] = s4 + v4;
    }
  }
}

// ---------------------------------------------------------------------------
extern "C" void kernel_launch(void* const* d_in, const int* in_sizes, int n_in,
                              void* d_out, int out_size, void* d_ws, size_t ws_size,
                              hipStream_t stream)
{
  const float* x          = (const float*)d_in[0];
  const float* W_in       = (const float*)d_in[1];
  const float* b_in       = (const float*)d_in[2];
  const float* ln_g       = (const float*)d_in[3];
  const float* ln_b       = (const float*)d_in[4];
  const float* W_innov    = (const float*)d_in[5];
  const float* b_innov    = (const float*)d_in[6];
  const float* W_c1       = (const float*)d_in[7];
  const float* b_c1       = (const float*)d_in[8];
  const float* W_c2       = (const float*)d_in[9];
  const float* b_c2       = (const float*)d_in[10];
  const float* corr_scale = (const float*)d_in[11];
  const float* rawL       = (const float*)d_in[12];
  const float* rawT       = (const float*)d_in[13];
  const float* rawG       = (const float*)d_in[14];
  const float* rawR       = (const float*)d_in[15];
  const float* omega      = (const float*)d_in[16];

  unsigned short* hp = (unsigned short*)d_ws;
  float* bx = (float*)((char*)d_ws + (size_t)B_ * S_ * H_ * 2);

  int nblocksA = (B_ * S_) / TOKB;   // 2048
  phaseA<<<nblocksA, 256, 0, stream>>>(x, W_in, b_in, ln_g, ln_b,
                                       W_innov, b_innov, W_c1, b_c1, hp, bx);
  phaseB<<<B_, 64, 0, stream>>>(hp, bx, W_c1, W_c2, b_c2, corr_scale,
                                rawL, rawT, rawG, rawR, omega, (float*)d_out);
}

// Round 11
// 318.855 us; speedup vs baseline: 1.1260x; 1.1260x over previous
//
#include <hip/hip_runtime.h>
#include <hip/hip_bf16.h>

#define B_   256
#define S_   2048
#define DIN  128
#define H_   64
#define SD_  5
#define GDT  16            // steps per group (= one staging tile)
#define NTT  (S_ / GDT)    // 128 groups
#define TOKB 256           // tokens per phaseA block
#define NIT  4             // tiles per wave in phaseA

typedef __attribute__((ext_vector_type(8))) short short8_t;   // 8 bf16
typedef __attribute__((ext_vector_type(4))) float float4_t;   // MFMA acc

__device__ __forceinline__ float rcpf_(float x){ return __builtin_amdgcn_rcpf(x); }

// exact-erf GELU: gelu(x)=0.5x(1+erf(x/sqrt2)), A&S 7.1.26
__device__ __forceinline__ float geluf(float v){
  const float kInvSqrt2 = 0.70710678118654752440f;
  float z = v * kInvSqrt2;
  float a = fabsf(z);
  float t = rcpf_(fmaf(0.3275911f, a, 1.0f));
  float p = fmaf(fmaf(fmaf(fmaf(1.061405429f, t, -1.453152027f), t, 1.421413741f),
                      t, -0.284496736f), t, 0.254829592f);
  p *= t;
  float e = 1.0f - p * __expf(-z * z);
  float er = copysignf(e, z);
  return 0.5f * v * (1.0f + er);
}

__device__ __forceinline__ float sigmoidf_(float x){
  return rcpf_(1.0f + __expf(-x));
}

// Pade(3,2) tanh with clamp: |err| <= 0.0065 (attenuated x0.01 by corr_scale)
__device__ __forceinline__ float tanh_pade(float x){
  float xc = fminf(fmaxf(x, -4.0f), 4.0f);
  float t = xc * xc;
  float n = xc * (27.0f + t);
  float d = fmaf(9.0f, t, 27.0f);
  return n * rcpf_(d);
}

__device__ __forceinline__ unsigned short f2bf_hw(float f){
  union { __hip_bfloat16 b; unsigned short u; } cv;
  cv.b = __float2bfloat16(f);
  return cv.u;
}
__device__ __forceinline__ float bf2f(unsigned short h){
  return __uint_as_float(((unsigned int)h) << 16);
}

// ---- async global->LDS ----
__device__ __forceinline__ void gl_lds16(const void* g, void* l){
  __builtin_amdgcn_global_load_lds(
      (const __attribute__((address_space(1))) void*)g,
      (__attribute__((address_space(3))) void*)l, 16, 0, 0);
}
__device__ __forceinline__ void gl_lds4(const void* g, void* l){
  __builtin_amdgcn_global_load_lds(
      (const __attribute__((address_space(1))) void*)g,
      (__attribute__((address_space(3))) void*)l, 4, 0, 0);
}

// ---- DPP helpers ----
template<int CTRL>
__device__ __forceinline__ float dpp_radd(float x){
  int sh = __builtin_amdgcn_update_dpp(0, __float_as_int(x), CTRL, 0xf, 0xf, true);
  return x + __int_as_float(sh);
}
__device__ __forceinline__ float red16(float x){
  x = dpp_radd<0xB1>(x);   // quad_perm xor1
  x = dpp_radd<0x4E>(x);   // quad_perm xor2
  x = dpp_radd<0x124>(x);  // row_ror:4
  x = dpp_radd<0x128>(x);  // row_ror:8
  return x;
}

// raw barrier: drain LDS ops, barrier, pin the scheduler (keeps vmcnt counted)
#define BARRIER() do{                                   \
  asm volatile("s_waitcnt lgkmcnt(0)" ::: "memory");    \
  __builtin_amdgcn_s_barrier();                         \
  __builtin_amdgcn_sched_barrier(0);                    \
}while(0)

// ---------------------------------------------------------------------------
// Phase A (unchanged, MFMA-based)
// ---------------------------------------------------------------------------
__global__ __launch_bounds__(256, 4) void phaseA(
    const float* __restrict__ x, const float* __restrict__ W_in,
    const float* __restrict__ b_in, const float* __restrict__ ln_g,
    const float* __restrict__ ln_b, const float* __restrict__ W_innov,
    const float* __restrict__ b_innov, const float* __restrict__ W_c1,
    const float* __restrict__ b_c1,
    unsigned short* __restrict__ hp_out, float* __restrict__ bx_out)
{
  __shared__ __align__(16) unsigned short WfA[4][4][512];
  __shared__ __align__(16) unsigned short WfC[2][4][512];
  __shared__ __align__(16) unsigned short WfI[2][512];
  __shared__ __align__(16) unsigned short hbuf[4][16][72];

  const int tid  = threadIdx.x;
  const int lane = tid & 63;
  const int w    = tid >> 6;
  const int c16  = lane & 15;
  const int g4   = lane >> 4;
  const long tok0 = (long)blockIdx.x * TOKB;

  {
    const int l = lane, tg = w;
    #pragma unroll
    for (int pp = 0; pp < 4; ++pp){
      int p  = tg * 4 + pp;
      int kc = p >> 2, nc = p & 3;
      unsigned short tmp[8];
      #pragma unroll
      for (int m = 0; m < 8; ++m)
        tmp[m] = f2bf_hw(W_in[(32 * kc + 8 * (l >> 4) + m) * 64 + 16 * nc + (l & 15)]);
      *(uint4*)&WfA[kc][nc][l * 8] = *(uint4*)tmp;
    }
    #pragma unroll
    for (int pp = 0; pp < 2; ++pp){
      int p  = tg * 2 + pp;
      int kc2 = p >> 2, nc = p & 3;
      unsigned short tmp[8];
      #pragma unroll
      for (int m = 0; m < 8; ++m)
        tmp[m] = f2bf_hw(W_c1[(5 + 32 * kc2 + 8 * (l >> 4) + m) * 64 + 16 * nc + (l & 15)]);
      *(uint4*)&WfC[kc2][nc][l * 8] = *(uint4*)tmp;
    }
    if (tg < 2){
      int kc2 = tg;
      unsigned short tmp[8];
      #pragma unroll
      for (int m = 0; m < 8; ++m)
        tmp[m] = ((l & 15) < 5)
               ? f2bf_hw(W_innov[(32 * kc2 + 8 * (l >> 4) + m) * 5 + (l & 15)])
               : (unsigned short)0;
      *(uint4*)&WfI[kc2][l * 8] = *(uint4*)tmp;
    }
  }

  float binv[4], lg[4], lb[4], bc1v[4];
  #pragma unroll
  for (int nc = 0; nc < 4; ++nc){
    binv[nc] = b_in[16 * nc + c16];
    lg[nc]   = ln_g[16 * nc + c16];
    lb[nc]   = ln_b[16 * nc + c16];
    bc1v[nc] = b_c1[16 * nc + c16];
  }
  float binn = (c16 < 5) ? b_innov[c16] : 0.0f;

  __syncthreads();

  for (int it = 0; it < NIT; ++it){
    const long tbg = tok0 + it * 64 + w * 16;

    const float* xr = x + (size_t)(tbg + c16) * DIN;
    short8_t a1[4];
    #pragma unroll
    for (int kc = 0; kc < 4; ++kc){
      float4 f0 = *(const float4*)(xr + kc * 32 + g4 * 8);
      float4 f1 = *(const float4*)(xr + kc * 32 + g4 * 8 + 4);
      a1[kc][0] = (short)f2bf_hw(f0.x); a1[kc][1] = (short)f2bf_hw(f0.y);
      a1[kc][2] = (short)f2bf_hw(f0.z); a1[kc][3] = (short)f2bf_hw(f0.w);
      a1[kc][4] = (short)f2bf_hw(f1.x); a1[kc][5] = (short)f2bf_hw(f1.y);
      a1[kc][6] = (short)f2bf_hw(f1.z); a1[kc][7] = (short)f2bf_hw(f1.w);
    }

    float4_t acc1[4] = {{0,0,0,0},{0,0,0,0},{0,0,0,0},{0,0,0,0}};
    #pragma unroll
    for (int kc = 0; kc < 4; ++kc){
      #pragma unroll
      for (int nc = 0; nc < 4; ++nc){
        short8_t bf = *(const short8_t*)&WfA[kc][nc][lane * 8];
        acc1[nc] = __builtin_amdgcn_mfma_f32_16x16x32_bf16(a1[kc], bf, acc1[nc], 0, 0, 0);
      }
    }

    float v[4][4];
    #pragma unroll
    for (int nc = 0; nc < 4; ++nc)
      #pragma unroll
      for (int r = 0; r < 4; ++r)
        v[nc][r] = acc1[nc][r] + binv[nc];

    float mu[4], rstd[4];
    #pragma unroll
    for (int r = 0; r < 4; ++r){
      float vs = (v[0][r] + v[1][r]) + (v[2][r] + v[3][r]);
      float qs = v[0][r] * v[0][r];
      qs = fmaf(v[1][r], v[1][r], qs);
      qs = fmaf(v[2][r], v[2][r], qs);
      qs = fmaf(v[3][r], v[3][r], qs);
      vs = red16(vs);
      qs = red16(qs);
      float m  = vs * (1.0f / 64.0f);
      float va = fmaxf(qs * (1.0f / 64.0f) - m * m, 0.0f);
      mu[r]   = m;
      rstd[r] = rsqrtf(va + 1e-5f);
    }

    #pragma unroll
    for (int nc = 0; nc < 4; ++nc)
      #pragma unroll
      for (int r = 0; r < 4; ++r){
        float hn = fmaf((v[nc][r] - mu[r]) * rstd[r], lg[nc], lb[nc]);
        hbuf[w][4 * g4 + r][16 * nc + c16] = f2bf_hw(geluf(hn));
      }

    short8_t a2[2];
    a2[0] = *(const short8_t*)&hbuf[w][c16][8 * g4];
    a2[1] = *(const short8_t*)&hbuf[w][c16][32 + 8 * g4];

    float4_t acc2[4] = {{0,0,0,0},{0,0,0,0},{0,0,0,0},{0,0,0,0}};
    #pragma unroll
    for (int kc2 = 0; kc2 < 2; ++kc2){
      #pragma unroll
      for (int nc = 0; nc < 4; ++nc){
        short8_t bf = *(const short8_t*)&WfC[kc2][nc][lane * 8];
        acc2[nc] = __builtin_amdgcn_mfma_f32_16x16x32_bf16(a2[kc2], bf, acc2[nc], 0, 0, 0);
      }
    }
    float4_t acc3 = {0, 0, 0, 0};
    {
      short8_t bi0 = *(const short8_t*)&WfI[0][lane * 8];
      short8_t bi1 = *(const short8_t*)&WfI[1][lane * 8];
      acc3 = __builtin_amdgcn_mfma_f32_16x16x32_bf16(a2[0], bi0, acc3, 0, 0, 0);
      acc3 = __builtin_amdgcn_mfma_f32_16x16x32_bf16(a2[1], bi1, acc3, 0, 0, 0);
    }

    if (c16 < 5){
      #pragma unroll
      for (int r = 0; r < 4; ++r)
        bx_out[(size_t)(tbg + 4 * g4 + r) * 8 + c16] = acc3[r] + binn;
    }

    #pragma unroll
    for (int nc = 0; nc < 4; ++nc)
      #pragma unroll
      for (int r = 0; r < 4; ++r)
        hbuf[w][4 * g4 + r][16 * nc + c16] = f2bf_hw(acc2[nc][r] + bc1v[nc]);

    {
      const int tl = lane >> 2, j = lane & 3;
      uint4 v0 = *(const uint4*)&hbuf[w][tl][j * 16];
      uint4 v1 = *(const uint4*)&hbuf[w][tl][j * 16 + 8];
      unsigned short* hg = hp_out + (size_t)(tbg + tl) * 64 + j * 16;
      *(uint4*)hg       = v0;
      *(uint4*)(hg + 8) = v1;
    }
  }
}

// ---------------------------------------------------------------------------
// Phase B: producer-consumer, 2 waves per block (128 threads).
//   wave 0: ISSUE + 16-step recursion (reads crR, stages uT)
//   wave 1: CORR for the previous group (MFMA + tanh, publishes crR)
// Corrections injected 3 groups late (48 steps, A^48 twist) — numerics
// identical to the validated R10 kernel. One raw s_barrier per group;
// counted vmcnt preserved (no vmcnt(0) drain).
// Races: uT w0(t-1)->w1(t) 1 barrier; crR slot t%3 w1(t-2)->w0(t) 2 barriers;
// w0 reads slot (t-1)%3 at iter t-1, w1 overwrites it at iter t (1 barrier).
// ---------------------------------------------------------------------------
__global__ __launch_bounds__(128, 1) void phaseB(
    const unsigned short* __restrict__ hp, const float* __restrict__ bx,
    const float* __restrict__ W_c1, const float* __restrict__ W_c2,
    const float* __restrict__ b_c2, const float* __restrict__ corr_scale,
    const float* __restrict__ rawL, const float* __restrict__ rawT,
    const float* __restrict__ rawG, const float* __restrict__ rawR,
    const float* __restrict__ omega, float* __restrict__ out)
{
  __shared__ __align__(16) unsigned short hpT[2][GDT][64];  // 4 KB
  __shared__ __align__(16) float bxT[2][GDT][8];            // 1 KB
  __shared__ __align__(16) unsigned short uT[2][GDT][64];   // 4 KB (swizzled cols)
  __shared__ __align__(16) float crR[3][GDT][8];            // 1.5 KB ring

  const int tid  = threadIdx.x;
  const int lane = tid & 63;
  const int wid  = tid >> 6;
  const int b = blockIdx.x;
  const int c16 = lane & 15;
  const int g4  = lane >> 4;

  // zero-init the correction ring (384 floats, 128 threads x 3)
  ((float*)crR)[tid]       = 0.f;
  ((float*)crR)[tid + 128] = 0.f;
  ((float*)crR)[tid + 256] = 0.f;

  float aL = sigmoidf_(rawL[0]) * 0.15f + 0.85f;
  float aT = sigmoidf_(rawT[0]) * 0.25f + 0.70f;
  float gg = sigmoidf_(rawG[0]) * 0.20f + 0.80f;
  float om = omega[0];
  float co = cosf(om), sn = sinf(om);
  float r00 = gg * co, r01 = -gg * sn, r10 = gg * sn, r11 = gg * co;
  float aR = sigmoidf_(rawR[0]) * 0.4f;
  float cs = corr_scale[0];

  // A^48 for the 3-group (48-step) delayed injection
  auto p16f = [](float v){ float t = v * v; t = t * t; t = t * t; return t * t; };
  float aL16 = p16f(aL), aT16 = p16f(aT), aR16 = p16f(aR), g16 = p16f(gg);
  float aL48 = aL16 * aL16 * aL16;
  float aT48 = aT16 * aT16 * aT16;
  float aR48 = aR16 * aR16 * aR16;
  float g48  = g16 * g16 * g16;
  float ck = cosf(48.0f * om), sk = sinf(48.0f * om);
  float p00 = g48 * ck, p01 = -g48 * sk, p10 = g48 * sk, p11 = g48 * ck;

  float w0 = W_c1[0 * 64 + lane], w1 = W_c1[1 * 64 + lane], w2 = W_c1[2 * 64 + lane];
  float w3 = W_c1[3 * 64 + lane], w4 = W_c1[4 * 64 + lane];
  float bc0 = b_c2[0], bc1 = b_c2[1], bc2v = b_c2[2], bc3 = b_c2[3], bc4 = b_c2[4];
  float bcs0 = (g4 == 1) ? bc4 : bc0;   // acc reg0 = row i=4*g4

  // static A-frags for CORR (wave 1): W_c2^T, K split j 0..31 / 32..63
  short8_t aF0, aF1;
  #pragma unroll
  for (int m = 0; m < 8; ++m){
    int j0 = 8 * g4 + m;
    float v0 = (c16 < 5) ? W_c2[j0 * 5 + c16] : 0.0f;
    float v1 = (c16 < 5) ? W_c2[(j0 + 32) * 5 + c16] : 0.0f;
    aF0[m] = (short)f2bf_hw(v0);
    aF1[m] = (short)f2bf_hw(v1);
  }

  const unsigned short* hpg = hp + (size_t)b * S_ * H_;
  const float* bxg = bx + (size_t)b * S_ * 8;

  float s0 = 0.f, s1 = 0.f, s2 = 0.f, s3 = 0.f, s4 = 0.f;

  auto ISSUE = [&](int t, int nb){
    const unsigned short* g0 = hpg + (size_t)t * (GDT * 64) + lane * 8;
    gl_lds16(g0,       &hpT[nb][0][0]);
    gl_lds16(g0 + 512, &hpT[nb][8][0]);
    const float* g1 = bxg + (size_t)t * (GDT * 8) + lane;
    gl_lds4(g1,      &bxT[nb][0][0]);
    gl_lds4(g1 + 64, &bxT[nb][8][0]);
  };

  auto RECUR = [&](int rsl, int ub, int tbuf){
    float4 cp[GDT]; float cp4[GDT];
    #pragma unroll
    for (int k = 0; k < GDT; ++k){
      cp[k]  = *(const float4*)&crR[rsl][k][0];
      cp4[k] = crR[rsl][k][4];
    }
    float hk[GDT], e4v[GDT]; float4 xb[GDT];
    #pragma unroll
    for (int k = 0; k < GDT; ++k){
      hk[k]  = bf2f(hpT[tbuf][k][lane]);
      xb[k]  = *(const float4*)&bxT[tbuf][k][0];
      e4v[k] = bxT[tbuf][k][4];
    }
    float i0[GDT], i1[GDT], i2[GDT], i3[GDT], i4[GDT];
    #pragma unroll
    for (int k = 0; k < GDT; ++k){
      i0[k] = fmaf(cp[k].x, aL48, xb[k].x);
      i1[k] = fmaf(cp[k].y, aT48, xb[k].y);
      i2[k] = fmaf(cp[k].z, p00, fmaf(cp[k].w, p10, xb[k].z));
      i3[k] = fmaf(cp[k].z, p01, fmaf(cp[k].w, p11, xb[k].w));
      i4[k] = fmaf(cp4[k], aR48, e4v[k]);
    }
    float n0[GDT], n1[GDT], n2[GDT], n3[GDT], n4[GDT];
    #pragma unroll
    for (int k = 0; k < GDT; ++k){
      n0[k] = fmaf(s0, aL, i0[k]);
      n1[k] = fmaf(s1, aT, i1[k]);
      n2[k] = fmaf(s2, r00, fmaf(s3, r10, i2[k]));
      n3[k] = fmaf(s2, r01, fmaf(s3, r11, i3[k]));
      n4[k] = fmaf(s4, aR, i4[k]);
      s0 = n0[k]; s1 = n1[k]; s2 = n2[k]; s3 = n3[k]; s4 = n4[k];
    }
    #pragma unroll
    for (int k = 0; k < GDT; ++k){
      float u = fmaf(n0[k], w0, hk[k]);
      u = fmaf(n1[k], w1, u);
      u = fmaf(n2[k], w2, u);
      u = fmaf(n3[k], w3, u);
      u = fmaf(n4[k], w4, u);
      float uu = u * rcpf_(1.0f + __expf(-1.702f * u));   // sigmoid-GELU
      const int jsw = lane ^ ((k & 7) << 3);              // bank swizzle
      uT[ub][k][jsw] = (unsigned short)(__float_as_uint(uu) >> 16);
    }
  };

  auto CORR = [&](int wsl, int ub){
    const int blk0 = (g4 ^ (c16 & 7)) * 8;
    const int blk1 = ((4 + g4) ^ (c16 & 7)) * 8;
    short8_t b0 = *(const short8_t*)&uT[ub][c16][blk0];
    short8_t b1 = *(const short8_t*)&uT[ub][c16][blk1];
    float4_t acc = {0.f, 0.f, 0.f, 0.f};
    acc = __builtin_amdgcn_mfma_f32_16x16x32_bf16(aF0, b0, acc, 0, 0, 0);
    acc = __builtin_amdgcn_mfma_f32_16x16x32_bf16(aF1, b1, acc, 0, 0, 0);
    float d0 = cs * tanh_pade(acc[0] + bcs0);
    float d1 = cs * tanh_pade(acc[1] + bc1);
    float d2 = cs * tanh_pade(acc[2] + bc2v);
    float d3 = cs * tanh_pade(acc[3] + bc3);
    if (g4 == 0)
      *(float4*)&crR[wsl][c16][0] = make_float4(d0, d1, d2, d3);  // i=0..3, k=c16
    if (g4 == 1)
      crR[wsl][c16][4] = d0;                                      // i=4
  };

  __syncthreads();   // crR zeros visible to all

  // ---- prologue: g=0 ----
  if (wid == 0){
    ISSUE(0, 0);
    ISSUE(1, 1);
    asm volatile("s_waitcnt vmcnt(4)" ::: "memory");
    __builtin_amdgcn_sched_barrier(0);
    RECUR(0, 0, 0);           // g=0: reads crR[0] (zeros), stages uT[0]
  }

  int rs = 0, ws = 0;
  for (int t = 1; t < NTT; ++t){
    rs = (rs == 2) ? 0 : rs + 1;      // = t%3
    BARRIER();
    if (wid == 0){
      int tn = (t + 1 < NTT) ? (t + 1) : 0;
      ISSUE(tn, (t + 1) & 1);
      asm volatile("s_waitcnt vmcnt(4)" ::: "memory");
      __builtin_amdgcn_sched_barrier(0);
      RECUR(rs, t & 1, t & 1);        // g=t
    } else {
      CORR(ws, (t - 1) & 1);          // g=t-1 -> crR[(t-1)%3]
    }
    ws = (ws == 2) ? 0 : ws + 1;      // after iter t: ws = t%3
  }
  BARRIER();
  if (wid == 1) CORR(ws, (NTT - 1) & 1);   // g=NTT-1, ws=(NTT-1)%3
  BARRIER();

  // ---- tail: s_final = s_hat + Horner(last 48 corrections under A) ----
  if (wid == 0){
    const int sl0 = (NTT - 3) % 3, sl1 = (NTT - 2) % 3, sl2 = (NTT - 1) % 3;
    const int sl[3] = { sl0, sl1, sl2 };
    float v0 = 0.f, v1 = 0.f, v2 = 0.f, v3 = 0.f, v4 = 0.f;
    #pragma unroll
    for (int gi = 0; gi < 3; ++gi){
      const int sli = sl[gi];
      #pragma unroll
      for (int k = 0; k < GDT; ++k){
        float n0 = fmaf(v0, aL, crR[sli][k][0]);
        float n1 = fmaf(v1, aT, crR[sli][k][1]);
        float n2 = fmaf(v2, r00, fmaf(v3, r10, crR[sli][k][2]));
        float n3 = fmaf(v2, r01, fmaf(v3, r11, crR[sli][k][3]));
        float n4 = fmaf(v4, aR, crR[sli][k][4]);
        v0 = n0; v1 = n1; v2 = n2; v3 = n3; v4 = n4;
      }
    }
    if (lane == 0){
      float* o = out + b * SD_;
      o[0] = s0 + v0; o[1] = s1 + v1; o[2] = s2 + v2;
      o[3] = s3 + v3; o[4] = s4 + v4;
    }
  }
}

// ---------------------------------------------------------------------------
extern "C" void kernel_launch(void* const* d_in, const int* in_sizes, int n_in,
                              void* d_out, int out_size, void* d_ws, size_t ws_size,
                              hipStream_t stream)
{
  const float* x          = (const float*)d_in[0];
  const float* W_in       = (const float*)d_in[1];
  const float* b_in       = (const float*)d_in[2];
  const float* ln_g       = (const float*)d_in[3];
  const float* ln_b       = (const float*)d_in[4];
  const float* W_innov    = (const float*)d_in[5];
  const float* b_innov    = (const float*)d_in[6];
  const float* W_c1       = (const float*)d_in[7];
  const float* b_c1       = (const float*)d_in[8];
  const float* W_c2       = (const float*)d_in[9];
  const float* b_c2       = (const float*)d_in[10];
  const float* corr_scale = (const float*)d_in[11];
  const float* rawL       = (const float*)d_in[12];
  const float* rawT       = (const float*)d_in[13];
  const float* rawG       = (const float*)d_in[14];
  const float* rawR       = (const float*)d_in[15];
  const float* omega      = (const float*)d_in[16];

  unsigned short* hp = (unsigned short*)d_ws;
  float* bx = (float*)((char*)d_ws + (size_t)B_ * S_ * H_ * 2);

  int nblocksA = (B_ * S_) / TOKB;   // 2048
  phaseA<<<nblocksA, 256, 0, stream>>>(x, W_in, b_in, ln_g, ln_b,
                                       W_innov, b_innov, W_c1, b_c1, hp, bx);
  phaseB<<<B_, 128, 0, stream>>>(hp, bx, W_c1, W_c2, b_c2, corr_scale,
                                 rawL, rawT, rawG, rawR, omega, (float*)d_out);
}